// Round 5
// baseline (945.265 us; speedup 1.0000x reference)
//
#include <hip/hip_runtime.h>
#include <hip/hip_bf16.h>
#include <math.h>

// Problem constants
#define E_   131072
#define CH_  16384            // edge chunk for the He GEMM (8 chunks)
#define N_   600
#define NB_  2
#define NQ_  300
#define NK_  1024
#define NH_  8

typedef __hip_bfloat16 bf16;
typedef __bf16 bh8 __attribute__((ext_vector_type(8)));
typedef float  fx4 __attribute__((ext_vector_type(4)));

static __device__ __forceinline__ float b2f(bf16 x){ return __bfloat162float(x); }
static __device__ __forceinline__ unsigned pack2(float x, float y){
  unsigned a = __bfloat16_as_ushort(__float2bfloat16(x));
  unsigned b = __bfloat16_as_ushort(__float2bfloat16(y));
  return a | (b << 16);
}
// dual-dtype scalar load: isf32 ? f32[i] : bf16[i]
static __device__ __forceinline__ float ldf(const void* p, size_t i, bool isf32){
  return isf32 ? ((const float*)p)[i] : b2f(((const bf16*)p)[i]);
}

// ---- converted-weight table offsets (elements) ----
constexpr int WOFF[31] = {
  0,256,512,768,1024,1280,
  1536,67072,67328,132864,
  133120,133376,
  133632,264704,
  264960,330496,330752,396288,
  396544,527616,
  528128,528640,528896,530944,
  530952,596488,
  596744,858888,859912,1122056,
  1122312};
#define NWSEG 30
#define WTOT  1122312
struct SrcTab { const void* p[NWSEG]; };

// block-wide LayerNorm stats over 256 values (one per thread), 4 waves
static __device__ __forceinline__ void ln_stats(float v, int t, float* r1, float* r2,
                                                float& mu, float& rstd){
  float s1 = v, s2 = v*v;
  #pragma unroll
  for (int o = 32; o; o >>= 1){ s1 += __shfl_down(s1, o); s2 += __shfl_down(s2, o); }
  if ((t & 63) == 0){ r1[t>>6] = s1; r2[t>>6] = s2; }
  __syncthreads();
  float t1 = r1[0]+r1[1]+r1[2]+r1[3];
  float t2 = r2[0]+r2[1]+r2[2]+r2[3];
  mu = t1 * (1.f/256.f);
  float var = t2 * (1.f/256.f) - mu*mu;
  rstd = rsqrtf(var + 1e-5f);
  __syncthreads();
}

__global__ void k_init(int* cnt, unsigned* mkey, float* denom,
                       const void* nodes, int* dflag){
  int i = blockIdx.x*256 + threadIdx.x;
  if (i < N_) cnt[i] = 0;
  if (i < N_*NH_){ mkey[i] = 0u; denom[i] = 0.f; }
  if (i == 0){
    const unsigned short* h = (const unsigned short*)nodes;
    int odd = 0;
    for (int j = 0; j < 64; j++){
      int e = (h[j] >> 7) & 0xFF;
      if (e < 100 || e > 150) odd++;
    }
    *dflag = (odd > 8) ? 1 : 0;   // 1 = f32 storage, 0 = bf16 storage
  }
}

__global__ __launch_bounds__(256) void k_cvt(SrcTab tab, float* wall, const int* dflag){
  int i = blockIdx.x*256 + threadIdx.x;
  if (i >= WTOT) return;
  bool isf32 = (*dflag != 0);
  int seg = 0;
  while (seg < NWSEG-1 && i >= WOFF[seg+1]) seg++;
  wall[i] = ldf(tab.p[seg], (size_t)(i - WOFF[seg]), isf32);
}

__global__ __launch_bounds__(256) void k_node_pre(
    const void* __restrict__ nodes, const int* __restrict__ dflag,
    const float* __restrict__ g1, const float* __restrict__ b1,
    const float* __restrict__ Wni, const float* __restrict__ Wnj, const float* __restrict__ Wmsg,
    float* __restrict__ Pni, float* __restrict__ Pnj, float* __restrict__ Pmsg)
{
  __shared__ float xs[256];
  __shared__ float r1[4], r2[4];
  int n = blockIdx.x, t = threadIdx.x;
  bool isf32 = (*dflag != 0);
  float v = ldf(nodes, (size_t)n*256 + t, isf32);
  float mu, rstd;
  ln_stats(v, t, r1, r2, mu, rstd);
  float xv = (v - mu) * rstd * g1[t] + b1[t];
  xs[t] = xv;
  __syncthreads();
  float a0 = 0.f, a1 = 0.f, a2 = 0.f;
  for (int k = 0; k < 256; k++){
    float xk = xs[k];
    a0 = fmaf(xk, Wni[k*256 + t], a0);
    a1 = fmaf(xk, Wnj[k*256 + t], a1);
    a2 = fmaf(xk, Wmsg[k*256 + t], a2);
  }
  Pni[n*256 + t] = a0; Pnj[n*256 + t] = a1; Pmsg[n*256 + t] = a2;
}

__global__ void k_prep(const void* __restrict__ We, const int* __restrict__ dflag,
                       const float* __restrict__ bni, const float* __restrict__ bnj,
                       const float* __restrict__ be,
                       bf16* __restrict__ WeT, float* __restrict__ biasH)
{
  int k = blockIdx.x, n = threadIdx.x;
  bool isf32 = (*dflag != 0);
  WeT[n*256 + k] = __float2bfloat16(ldf(We, (size_t)k*256 + n, isf32));
  if (k == 0) biasH[n] = bni[n] + bnj[n] + be[n];
}

__global__ void k_count(const int* __restrict__ ei, int* cnt){
  int e = blockIdx.x*256 + threadIdx.x;
  atomicAdd(&cnt[ei[e]], 1);
}

__global__ __launch_bounds__(1024) void k_scan(const int* __restrict__ cnt,
                                               int* offs, int* cursor){
  __shared__ int s[1024];
  int t = threadIdx.x;
  s[t] = (t < N_) ? cnt[t] : 0;
  __syncthreads();
  for (int o = 1; o < 1024; o <<= 1){
    int v = 0;
    if (t >= o) v = s[t - o];
    __syncthreads();
    if (t >= o) s[t] += v;
    __syncthreads();
  }
  if (t < N_){ int excl = (t == 0) ? 0 : s[t-1]; offs[t] = excl; cursor[t] = excl; }
  if (t == N_-1) offs[N_] = s[N_-1];
}

__global__ void k_scatter(const int* __restrict__ ei, int* cursor, int* eorder){
  int e = blockIdx.x*256 + threadIdx.x;
  int pos = atomicAdd(&cursor[ei[e]], 1);
  eorder[pos] = e;
}

// MFMA GEMM: C[m][256] = A[m_base+m][256] @ B (BT bf16 pre-transposed), dual-dtype A
__global__ __launch_bounds__(256) void k_gemm_dual(
    const void* __restrict__ A, int m_base, const int* __restrict__ dflag,
    const bf16* __restrict__ BT, bf16* __restrict__ C)
{
  __shared__ __align__(16) bf16 As[128*40];
  __shared__ __align__(16) bf16 Bs[128*40];
  int m0 = blockIdx.x * 128;
  int n0 = blockIdx.y * 128;
  int t = threadIdx.x;
  bool isf32 = (*dflag != 0);
  int wave = t >> 6, lane = t & 63;
  int wr = (wave >> 1) * 64, wc = (wave & 1) * 64;
  int lm = lane & 15, lq = lane >> 4;
  int srow = t >> 2;            // 0..63
  int scol = (t & 3) * 8;       // 0,8,16,24
  size_t r0 = (size_t)(m_base + m0 + srow) * 256;
  size_t r1 = (size_t)(m_base + m0 + 64 + srow) * 256;
  fx4 acc[4][4] = {};
  for (int kk = 0; kk < 256; kk += 32){
    uint4 pa0, pa1;
    if (isf32){
      const float* a0p = (const float*)A + r0 + kk + scol;
      const float* a1p = (const float*)A + r1 + kk + scol;
      float4 va0a = *(const float4*)(a0p);
      float4 va0b = *(const float4*)(a0p + 4);
      float4 va1a = *(const float4*)(a1p);
      float4 va1b = *(const float4*)(a1p + 4);
      pa0.x = pack2(va0a.x, va0a.y); pa0.y = pack2(va0a.z, va0a.w);
      pa0.z = pack2(va0b.x, va0b.y); pa0.w = pack2(va0b.z, va0b.w);
      pa1.x = pack2(va1a.x, va1a.y); pa1.y = pack2(va1a.z, va1a.w);
      pa1.z = pack2(va1b.x, va1b.y); pa1.w = pack2(va1b.z, va1b.w);
    } else {
      pa0 = *(const uint4*)((const bf16*)A + r0 + kk + scol);
      pa1 = *(const uint4*)((const bf16*)A + r1 + kk + scol);
    }
    float4 vb0 = *(const float4*)(BT + (size_t)(n0 + srow)      * 256 + kk + scol);
    float4 vb1 = *(const float4*)(BT + (size_t)(n0 + 64 + srow) * 256 + kk + scol);
    __syncthreads();
    *(uint4*)(As + srow*40 + scol)         = pa0;
    *(uint4*)(As + (64 + srow)*40 + scol)  = pa1;
    *(float4*)(Bs + srow*40 + scol)        = vb0;
    *(float4*)(Bs + (64 + srow)*40 + scol) = vb1;
    __syncthreads();
    bh8 af[4], bfr[4];
    #pragma unroll
    for (int mt = 0; mt < 4; mt++)
      af[mt] = *reinterpret_cast<const bh8*>(As + (wr + mt*16 + lm)*40 + lq*8);
    #pragma unroll
    for (int nt = 0; nt < 4; nt++)
      bfr[nt] = *reinterpret_cast<const bh8*>(Bs + (wc + nt*16 + lm)*40 + lq*8);
    #pragma unroll
    for (int mt = 0; mt < 4; mt++)
      #pragma unroll
      for (int nt = 0; nt < 4; nt++)
        acc[mt][nt] = __builtin_amdgcn_mfma_f32_16x16x32_bf16(af[mt], bfr[nt], acc[mt][nt], 0, 0, 0);
  }
  #pragma unroll
  for (int mt = 0; mt < 4; mt++)
    #pragma unroll
    for (int nt = 0; nt < 4; nt++)
      #pragma unroll
      for (int r = 0; r < 4; r++){
        int row = m0 + wr + mt*16 + lq*4 + r;
        int col = n0 + wc + nt*16 + lm;
        C[(size_t)row*256 + col] = __float2bfloat16(acc[mt][nt][r]);
      }
}

__global__ __launch_bounds__(256) void k_logits(
    const bf16* __restrict__ He, const float* __restrict__ Pni, const float* __restrict__ Pnj,
    const float* __restrict__ biasH, const float* __restrict__ ap, const int* __restrict__ ei,
    float* __restrict__ logits, unsigned* __restrict__ mkey, int e0chunk)
{
  int gid = blockIdx.x*256 + threadIdx.x;   // CH_*8
  int el = gid >> 3, h = gid & 7;
  int e = e0chunk + el;
  int s = ei[e], d = ei[E_ + e];
  const bf16*  her = He  + (size_t)el*256 + h*32;
  const float* pn  = Pni + s*256 + h*32;
  const float* pj  = Pnj + d*256 + h*32;
  const float* bh  = biasH + h*32;
  const float* apr = ap + h*32;
  float acc = 0.f;
  #pragma unroll
  for (int i = 0; i < 32; i++){
    float v = b2f(her[i]) + pn[i] + pj[i] + bh[i];
    v = (v > 0.f) ? v : 0.2f * v;        // leaky_relu 0.2
    acc = fmaf(v, apr[i], acc);
  }
  logits[(size_t)e*8 + h] = acc;
  unsigned ub = __float_as_uint(acc);
  unsigned key = (ub & 0x80000000u) ? ~ub : (ub | 0x80000000u);
  atomicMax(&mkey[s*8 + h], key);
}

__global__ __launch_bounds__(256) void k_softden(
    const int* __restrict__ ei, float* __restrict__ logits,
    const unsigned* __restrict__ mkey, float* __restrict__ denom)
{
  int gid = blockIdx.x*256 + threadIdx.x;
  int e = gid >> 3, h = gid & 7;
  int s = ei[e];
  unsigned key = mkey[s*8 + h];
  unsigned ub = (key & 0x80000000u) ? (key & 0x7FFFFFFFu) : ~key;
  float m = __uint_as_float(ub);
  float a = fminf(logits[gid] - m, 0.f);
  float z = __expf(a);
  logits[gid] = z;
  atomicAdd(&denom[s*8 + h], z);
}

__global__ __launch_bounds__(256) void k_agg(
    const int* __restrict__ offs, const int* __restrict__ eorder, const int* __restrict__ ei,
    const float* __restrict__ z, const float* __restrict__ denom,
    const void* __restrict__ ef, const int* __restrict__ dflag,
    const float* __restrict__ Pmsg, const float* __restrict__ bmsg,
    const float* __restrict__ Wmsg,
    const void* __restrict__ nodes, const float* __restrict__ Wg, const float* __restrict__ bg,
    const float* __restrict__ g2, const float* __restrict__ b2v,
    const float* __restrict__ Wq, const float* __restrict__ bq,
    float* __restrict__ nodes1, float* __restrict__ qbuf)
{
  __shared__ float zsh[32*8];
  __shared__ int   esh[32];
  __shared__ int   dsh[32];
  __shared__ float sinv[8];
  __shared__ float Fs[8*257];
  __shared__ float aggs[256];
  __shared__ float r1[4], r2[4];
  int n = blockIdx.x, t = threadIdx.x;
  bool isf32 = (*dflag != 0);
  int h = t >> 5;
  int e0 = offs[n], e1 = offs[n+1];
  if (t < 8){
    float dsum = denom[n*8 + t];
    sinv[t] = (dsum > 0.f) ? 1.f/dsum : 0.f;
  }
  float facc[8] = {};
  float gacc = 0.f;
  int jz = t >> 3, hz = t & 7;
  for (int base = e0; base < e1; base += 32){
    int cnt = min(32, e1 - base);
    __syncthreads();
    if (t < cnt){ int e = eorder[base + t]; esh[t] = e; dsh[t] = ei[E_ + e]; }
    __syncthreads();
    if (jz < cnt) zsh[t] = z[(size_t)esh[jz]*8 + hz];
    __syncthreads();
    for (int jj = 0; jj < cnt; jj++){
      int e = esh[jj];
      float efv = ldf(ef, (size_t)e*256 + t, isf32);
      #pragma unroll
      for (int hq = 0; hq < 8; hq++) facc[hq] = fmaf(zsh[jj*8 + hq], efv, facc[hq]);
      gacc = fmaf(zsh[jj*8 + h], Pmsg[dsh[jj]*256 + t], gacc);
    }
  }
  __syncthreads();
  #pragma unroll
  for (int hq = 0; hq < 8; hq++) Fs[hq*257 + t] = facc[hq] * sinv[hq];
  __syncthreads();
  float am = gacc * sinv[h] + bmsg[t];
  const float* fr = Fs + h*257;
  for (int k = 0; k < 256; k++)
    am = fmaf(fr[k], Wmsg[(size_t)(256 + k)*256 + t], am);
  aggs[t] = am;
  __syncthreads();
  float o = bg[t] + ldf(nodes, (size_t)n*256 + t, isf32);
  for (int k = 0; k < 256; k++) o = fmaf(aggs[k], Wg[k*256 + t], o);
  nodes1[n*256 + t] = o;
  float mu, rstd;
  ln_stats(o, t, r1, r2, mu, rstd);
  float x2 = (o - mu) * rstd * g2[t] + b2v[t];
  __syncthreads();
  aggs[t] = x2;
  __syncthreads();
  float q = bq[t];
  for (int k = 0; k < 256; k++) q = fmaf(aggs[k], Wq[k*256 + t], q);
  qbuf[n*256 + t] = q;
}

__global__ __launch_bounds__(256) void k_kv(
    const void* __restrict__ images, const int* __restrict__ dflag,
    const float* __restrict__ Wkv, const float* __restrict__ bkv,
    float* __restrict__ kbuf, float* __restrict__ vT)
{
  __shared__ float im[256];
  int bk = blockIdx.x;
  int b = bk >> 10, ki = bk & 1023;
  int t = threadIdx.x;
  bool isf32 = (*dflag != 0);
  im[t] = ldf(images, (size_t)bk*256 + t, isf32);
  __syncthreads();
  float ko = bkv[t], vo = bkv[256 + t];
  for (int j = 0; j < 256; j++){
    float x = im[j];
    ko = fmaf(x, Wkv[j*512 + t], ko);
    vo = fmaf(x, Wkv[j*512 + 256 + t], vo);
  }
  kbuf[(size_t)bk*256 + t] = ko;
  int h = t >> 5, d = t & 31;
  vT[(((size_t)b*NH_ + h)*32 + d)*NK_ + ki] = vo;
}

__global__ __launch_bounds__(256) void k_cpb(
    const void* __restrict__ rel, const int* __restrict__ dflag,
    const float* __restrict__ Wc1, const float* __restrict__ bc1,
    const float* __restrict__ Wc2, const float* __restrict__ bc2, bf16* __restrict__ bias)
{
  __shared__ float w0[256], w1[256], bb[256], w2[256*8], b2s[8];
  int t = threadIdx.x;
  bool isf32 = (*dflag != 0);
  w0[t] = Wc1[t]; w1[t] = Wc1[256 + t]; bb[t] = bc1[t];
  for (int i = t; i < 2048; i += 256) w2[i] = Wc2[i];
  if (t < 8) b2s[t] = bc2[t];
  __syncthreads();
  size_t pos = (size_t)blockIdx.x*256 + t;
  float c0 = ldf(rel, pos*2, isf32), c1 = ldf(rel, pos*2 + 1, isf32);
  float acc[8] = {};
  for (int j = 0; j < 256; j++){
    float hj = fmaf(c0, w0[j], fmaf(c1, w1[j], bb[j]));
    hj = fmaxf(hj, 0.f);
    #pragma unroll
    for (int h = 0; h < 8; h++) acc[h] = fmaf(hj, w2[j*8 + h], acc[h]);
  }
  int k = (int)(pos & 1023);
  size_t qq = pos >> 10;
  size_t b = qq / NQ_, q = qq % NQ_;
  bf16* dst = bias + ((b*NH_)*NQ_ + q)*NK_;
  #pragma unroll
  for (int h = 0; h < 8; h++)
    dst[(size_t)h*NQ_*NK_ + k] = __float2bfloat16(acc[h] + b2s[h]);
}

__global__ __launch_bounds__(256) void k_attn(
    const float* __restrict__ qbuf, const float* __restrict__ kbuf, const float* __restrict__ vT,
    const bf16* __restrict__ bias, float* __restrict__ attn_out)
{
  __shared__ float qv[32];
  __shared__ float p[1024];
  __shared__ float rmx[4], rsm[4];
  int qi = blockIdx.x, h = blockIdx.y, b = blockIdx.z;
  int t = threadIdx.x;
  if (t < 32) qv[t] = qbuf[((size_t)b*NQ_ + qi)*256 + h*32 + t];
  __syncthreads();
  const float* kbase = kbuf + (size_t)b*NK_*256 + h*32;
  const bf16*  brow  = bias + (((size_t)b*NH_ + h)*NQ_ + qi)*NK_;
  float sc[4];
  float lmax = -1e30f;
  #pragma unroll
  for (int c = 0; c < 4; c++){
    int k = c*256 + t;
    const float* kr = kbase + (size_t)k*256;
    float s = 0.f;
    #pragma unroll
    for (int d = 0; d < 32; d++) s = fmaf(qv[d], kr[d], s);
    s = s * 0.17677669529663689f + b2f(brow[k]);
    sc[c] = s;
    lmax = fmaxf(lmax, s);
  }
  #pragma unroll
  for (int o = 32; o; o >>= 1) lmax = fmaxf(lmax, __shfl_down(lmax, o));
  if ((t & 63) == 0) rmx[t>>6] = lmax;
  __syncthreads();
  float bm = fmaxf(fmaxf(rmx[0], rmx[1]), fmaxf(rmx[2], rmx[3]));
  float lsum = 0.f;
  #pragma unroll
  for (int c = 0; c < 4; c++){
    float pz = __expf(fminf(sc[c] - bm, 0.f));
    p[c*256 + t] = pz;
    lsum += pz;
  }
  #pragma unroll
  for (int o = 32; o; o >>= 1) lsum += __shfl_down(lsum, o);
  if ((t & 63) == 0) rsm[t>>6] = lsum;
  __syncthreads();
  float inv = 1.f / (rsm[0] + rsm[1] + rsm[2] + rsm[3]);
  int d = t >> 3, kc = t & 7;
  const float* vr = vT + (((size_t)b*NH_ + h)*32 + d)*NK_;
  float o = 0.f;
  for (int j = 0; j < 128; j++) o = fmaf(p[j*8 + kc], vr[j*8 + kc], o);
  o += __shfl_xor(o, 1); o += __shfl_xor(o, 2); o += __shfl_xor(o, 4);
  if (kc == 0)
    attn_out[(((size_t)b*NH_ + h)*NQ_ + qi)*32 + d] = o * inv;
}

__global__ __launch_bounds__(256) void k_final(
    const float* __restrict__ attn_out, const float* __restrict__ nodes1,
    const float* __restrict__ Wco, const float* __restrict__ bco,
    const float* __restrict__ g3, const float* __restrict__ b3,
    const float* __restrict__ Wf1, const float* __restrict__ bf1v,
    const float* __restrict__ Wf2, const float* __restrict__ bf2v,
    float* __restrict__ out)
{
  __shared__ float ybuf[256];
  __shared__ float x3s[256];
  __shared__ float f1s[1024];
  __shared__ float r1[4], r2[4];
  int n = blockIdx.x;
  int b = n / NQ_, qp = n % NQ_;
  int t = threadIdx.x;
  // faithful reshape WITHOUT head transpose: c=j*32+d, tt=qp*8+j, h=tt/300, q=tt%300
  int j = t >> 5, d = t & 31;
  int tt = qp*8 + j;
  int hj = tt / NQ_, qj = tt % NQ_;
  ybuf[t] = attn_out[(((size_t)b*NH_ + hj)*NQ_ + qj)*32 + d];
  __syncthreads();
  float o = bco[t];
  for (int k = 0; k < 256; k++) o = fmaf(ybuf[k], Wco[k*256 + t], o);
  float n2 = nodes1[n*256 + t] + o;
  float mu, rstd;
  ln_stats(n2, t, r1, r2, mu, rstd);
  float x3 = (n2 - mu) * rstd * g3[t] + b3[t];
  x3s[t] = x3;
  __syncthreads();
  float a0 = bf1v[t], a1 = bf1v[256 + t], a2 = bf1v[512 + t], a3 = bf1v[768 + t];
  for (int k = 0; k < 256; k++){
    float xv = x3s[k];
    const float* wr = Wf1 + (size_t)k*1024;
    a0 = fmaf(xv, wr[t],       a0);
    a1 = fmaf(xv, wr[256 + t], a1);
    a2 = fmaf(xv, wr[512 + t], a2);
    a3 = fmaf(xv, wr[768 + t], a3);
  }
  const float c = 0.70710678118654752f;
  f1s[t]       = 0.5f*a0*(1.f + erff(a0*c));
  f1s[256 + t] = 0.5f*a1*(1.f + erff(a1*c));
  f1s[512 + t] = 0.5f*a2*(1.f + erff(a2*c));
  f1s[768 + t] = 0.5f*a3*(1.f + erff(a3*c));
  __syncthreads();
  float r = bf2v[t] + x3s[t];         // residual from the NORMED input
  for (int k = 0; k < 1024; k++) r = fmaf(f1s[k], Wf2[(size_t)k*256 + t], r);
  out[n*256 + t] = r;                 // OUTPUT IS FLOAT32 (reference returns f32)
}

extern "C" void kernel_launch(void* const* d_in, const int* in_sizes, int n_in,
                              void* d_out, int out_size, void* d_ws, size_t ws_size,
                              hipStream_t stream)
{
  const void* nodes  = d_in[0];
  const void* images = d_in[1];
  const void* rel    = d_in[2];
  const void* ef     = d_in[3];
  const int*  ei     = (const int*)d_in[4];
  float* out = (float*)d_out;

  char* w = (char*)d_ws;
  auto alloc = [&](size_t bytes) -> void* {
    void* p = (void*)w; w += (bytes + 255) & ~(size_t)255; return p;
  };
  int*      dflag  = (int*)     alloc(4);
  float*    Wall   = (float*)   alloc((size_t)WTOT*4);
  bf16*     He     = (bf16*)    alloc((size_t)CH_*256*2);
  bf16*     bias   = (bf16*)    alloc((size_t)NB_*NH_*NQ_*NK_*2);
  float*    logits = (float*)   alloc((size_t)E_*8*4);
  float*    Pni    = (float*)   alloc(N_*256*4);
  float*    Pnj    = (float*)   alloc(N_*256*4);
  float*    Pmsg   = (float*)   alloc(N_*256*4);
  float*    biasH  = (float*)   alloc(256*4);
  float*    nodes1 = (float*)   alloc(N_*256*4);
  float*    qbuf   = (float*)   alloc(N_*256*4);
  float*    kbuf   = (float*)   alloc((size_t)NB_*NK_*256*4);
  float*    vT     = (float*)   alloc((size_t)NB_*NH_*32*NK_*4);
  float*    attn_o = (float*)   alloc((size_t)NB_*NH_*NQ_*32*4);
  unsigned* mkey   = (unsigned*)alloc(N_*8*4);
  float*    denom  = (float*)   alloc(N_*8*4);
  int*      cnt    = (int*)     alloc(N_*4);
  int*      offs   = (int*)     alloc((N_+1)*4);
  int*      cursor = (int*)     alloc(N_*4);
  int*      eorder = (int*)     alloc((size_t)E_*4);
  bf16*     WeT    = (bf16*)    alloc(256*256*2);
  // total ~= 35.5 MB

  const float *ln1g=Wall+WOFF[0],  *ln1b=Wall+WOFF[1];
  const float *ln2g=Wall+WOFF[2],  *ln2b=Wall+WOFF[3];
  const float *ln3g=Wall+WOFF[4],  *ln3b=Wall+WOFF[5];
  const float *Wni=Wall+WOFF[6],  *bni=Wall+WOFF[7];
  const float *Wnj=Wall+WOFF[8],  *bnj=Wall+WOFF[9];
  const float *be =Wall+WOFF[10], *ap =Wall+WOFF[11];
  const float *Wmsg=Wall+WOFF[12], *bmsg=Wall+WOFF[13];
  const float *Wg=Wall+WOFF[14], *bg=Wall+WOFF[15];
  const float *Wq=Wall+WOFF[16], *bq=Wall+WOFF[17];
  const float *Wkv=Wall+WOFF[18], *bkv=Wall+WOFF[19];
  const float *Wc1=Wall+WOFF[20], *bc1=Wall+WOFF[21];
  const float *Wc2=Wall+WOFF[22], *bc2=Wall+WOFF[23];
  const float *Wco=Wall+WOFF[24], *bco=Wall+WOFF[25];
  const float *Wf1=Wall+WOFF[26], *bf1v=Wall+WOFF[27];
  const float *Wf2=Wall+WOFF[28], *bf2v=Wall+WOFF[29];

  SrcTab tab;
  {
    const int idx[NWSEG] = {6,7,8,9,10,11, 12,13,14,15, 17,18, 19,20, 21,22,23,24,
                            25,26, 27,28,29,30, 31,32, 33,34,35,36};
    for (int i = 0; i < NWSEG; i++) tab.p[i] = d_in[idx[i]];
  }

  k_init    <<<19, 256, 0, stream>>>(cnt, mkey, denom, nodes, dflag);
  k_cvt     <<<(WTOT+255)/256, 256, 0, stream>>>(tab, Wall, dflag);
  k_node_pre<<<N_, 256, 0, stream>>>(nodes, dflag, ln1g, ln1b, Wni, Wnj, Wmsg, Pni, Pnj, Pmsg);
  k_prep    <<<256, 256, 0, stream>>>(d_in[16], dflag, bni, bnj, be, WeT, biasH);
  k_count   <<<E_/256, 256, 0, stream>>>(ei, cnt);
  k_scan    <<<1, 1024, 0, stream>>>(cnt, offs, cursor);
  k_scatter <<<E_/256, 256, 0, stream>>>(ei, cursor, eorder);

  dim3 ggrid(CH_/128, 2);
  for (int c = 0; c < E_/CH_; c++){
    k_gemm_dual<<<ggrid, 256, 0, stream>>>(ef, c*CH_, dflag, WeT, He);
    k_logits   <<<CH_*8/256, 256, 0, stream>>>(He, Pni, Pnj, biasH, ap, ei, logits, mkey, c*CH_);
  }
  k_softden <<<E_*8/256, 256, 0, stream>>>(ei, logits, mkey, denom);
  k_agg     <<<N_, 256, 0, stream>>>(offs, eorder, ei, logits, denom, ef, dflag, Pmsg, bmsg, Wmsg,
                                     nodes, Wg, bg, ln2g, ln2b, Wq, bq, nodes1, qbuf);
  k_kv      <<<NB_*NK_, 256, 0, stream>>>(images, dflag, Wkv, bkv, kbuf, vT);
  k_cpb     <<<NB_*NQ_*NK_/256, 256, 0, stream>>>(rel, dflag, Wc1, bc1, Wc2, bc2, bias);
  dim3 agrid(NQ_, NH_, NB_);
  k_attn    <<<agrid, 256, 0, stream>>>(qbuf, kbuf, vT, bias, attn_o);
  k_final   <<<N_, 256, 0, stream>>>(attn_o, nodes1, Wco, bco, ln3g, ln3b,
                                     Wf1, bf1v, Wf2, bf2v, out);
}

// Round 6
// 820.422 us; speedup vs baseline: 1.1522x; 1.1522x over previous
//
#include <hip/hip_runtime.h>
#include <hip/hip_bf16.h>
#include <math.h>

// Problem constants
#define E_   131072
#define CH_  16384            // edge chunk for the He GEMM (8 chunks)
#define N_   600
#define NB_  2
#define NQ_  300
#define NK_  1024
#define NH_  8

typedef __hip_bfloat16 bf16;
typedef __bf16 bh8 __attribute__((ext_vector_type(8)));
typedef float  fx4 __attribute__((ext_vector_type(4)));

static __device__ __forceinline__ float b2f(bf16 x){ return __bfloat162float(x); }
static __device__ __forceinline__ unsigned pack2(float x, float y){
  unsigned a = __bfloat16_as_ushort(__float2bfloat16(x));
  unsigned b = __bfloat16_as_ushort(__float2bfloat16(y));
  return a | (b << 16);
}
// dual-dtype scalar load: isf32 ? f32[i] : bf16[i]
static __device__ __forceinline__ float ldf(const void* p, size_t i, bool isf32){
  return isf32 ? ((const float*)p)[i] : b2f(((const bf16*)p)[i]);
}

// ---- converted-weight table offsets (elements) ----
constexpr int WOFF[31] = {
  0,256,512,768,1024,1280,
  1536,67072,67328,132864,
  133120,133376,
  133632,264704,
  264960,330496,330752,396288,
  396544,527616,
  528128,528640,528896,530944,
  530952,596488,
  596744,858888,859912,1122056,
  1122312};
#define NWSEG 30
#define WTOT  1122312
struct SrcTab { const void* p[NWSEG]; };

// block-wide LayerNorm stats over 256 values (one per thread), 4 waves
static __device__ __forceinline__ void ln_stats(float v, int t, float* r1, float* r2,
                                                float& mu, float& rstd){
  float s1 = v, s2 = v*v;
  #pragma unroll
  for (int o = 32; o; o >>= 1){ s1 += __shfl_down(s1, o); s2 += __shfl_down(s2, o); }
  if ((t & 63) == 0){ r1[t>>6] = s1; r2[t>>6] = s2; }
  __syncthreads();
  float t1 = r1[0]+r1[1]+r1[2]+r1[3];
  float t2 = r2[0]+r2[1]+r2[2]+r2[3];
  mu = t1 * (1.f/256.f);
  float var = t2 * (1.f/256.f) - mu*mu;
  rstd = rsqrtf(var + 1e-5f);
  __syncthreads();
}

__global__ void k_init(int* cnt, unsigned* mkey, float* denom,
                       const void* nodes, int* dflag){
  int i = blockIdx.x*256 + threadIdx.x;
  if (i < N_) cnt[i] = 0;
  if (i < N_*NH_){ mkey[i] = 0u; denom[i] = 0.f; }
  if (i == 0){
    const unsigned short* h = (const unsigned short*)nodes;
    int odd = 0;
    for (int j = 0; j < 64; j++){
      int e = (h[j] >> 7) & 0xFF;
      if (e < 100 || e > 150) odd++;
    }
    *dflag = (odd > 8) ? 1 : 0;   // 1 = f32 storage, 0 = bf16 storage
  }
}

__global__ __launch_bounds__(256) void k_cvt(SrcTab tab, float* wall, const int* dflag){
  int i = blockIdx.x*256 + threadIdx.x;
  if (i >= WTOT) return;
  bool isf32 = (*dflag != 0);
  int seg = 0;
  while (seg < NWSEG-1 && i >= WOFF[seg+1]) seg++;
  wall[i] = ldf(tab.p[seg], (size_t)(i - WOFF[seg]), isf32);
}

__global__ __launch_bounds__(256) void k_node_pre(
    const void* __restrict__ nodes, const int* __restrict__ dflag,
    const float* __restrict__ g1, const float* __restrict__ b1,
    const float* __restrict__ Wni, const float* __restrict__ Wnj, const float* __restrict__ Wmsg,
    float* __restrict__ Pni, float* __restrict__ Pnj, float* __restrict__ Pmsg)
{
  __shared__ float xs[256];
  __shared__ float r1[4], r2[4];
  int n = blockIdx.x, t = threadIdx.x;
  bool isf32 = (*dflag != 0);
  float v = ldf(nodes, (size_t)n*256 + t, isf32);
  float mu, rstd;
  ln_stats(v, t, r1, r2, mu, rstd);
  float xv = (v - mu) * rstd * g1[t] + b1[t];
  xs[t] = xv;
  __syncthreads();
  float a0 = 0.f, a1 = 0.f, a2 = 0.f;
  for (int k = 0; k < 256; k++){
    float xk = xs[k];
    a0 = fmaf(xk, Wni[k*256 + t], a0);
    a1 = fmaf(xk, Wnj[k*256 + t], a1);
    a2 = fmaf(xk, Wmsg[k*256 + t], a2);
  }
  Pni[n*256 + t] = a0; Pnj[n*256 + t] = a1; Pmsg[n*256 + t] = a2;
}

__global__ void k_prep(const void* __restrict__ We, const int* __restrict__ dflag,
                       const float* __restrict__ bni, const float* __restrict__ bnj,
                       const float* __restrict__ be,
                       bf16* __restrict__ WeT, float* __restrict__ biasH)
{
  int k = blockIdx.x, n = threadIdx.x;
  bool isf32 = (*dflag != 0);
  WeT[n*256 + k] = __float2bfloat16(ldf(We, (size_t)k*256 + n, isf32));
  if (k == 0) biasH[n] = bni[n] + bnj[n] + be[n];
}

__global__ void k_count(const int* __restrict__ ei, int* cnt){
  int e = blockIdx.x*256 + threadIdx.x;
  atomicAdd(&cnt[ei[e]], 1);
}

__global__ __launch_bounds__(1024) void k_scan(const int* __restrict__ cnt,
                                               int* offs, int* cursor){
  __shared__ int s[1024];
  int t = threadIdx.x;
  s[t] = (t < N_) ? cnt[t] : 0;
  __syncthreads();
  for (int o = 1; o < 1024; o <<= 1){
    int v = 0;
    if (t >= o) v = s[t - o];
    __syncthreads();
    if (t >= o) s[t] += v;
    __syncthreads();
  }
  if (t < N_){ int excl = (t == 0) ? 0 : s[t-1]; offs[t] = excl; cursor[t] = excl; }
  if (t == N_-1) offs[N_] = s[N_-1];
}

__global__ void k_scatter(const int* __restrict__ ei, int* cursor, int* eorder){
  int e = blockIdx.x*256 + threadIdx.x;
  int pos = atomicAdd(&cursor[ei[e]], 1);
  eorder[pos] = e;
}

// MFMA GEMM: C[m][256] = A[m_base+m][256] @ B (BT bf16 pre-transposed), dual-dtype A
__global__ __launch_bounds__(256) void k_gemm_dual(
    const void* __restrict__ A, int m_base, const int* __restrict__ dflag,
    const bf16* __restrict__ BT, bf16* __restrict__ C)
{
  __shared__ __align__(16) bf16 As[128*40];
  __shared__ __align__(16) bf16 Bs[128*40];
  int m0 = blockIdx.x * 128;
  int n0 = blockIdx.y * 128;
  int t = threadIdx.x;
  bool isf32 = (*dflag != 0);
  int wave = t >> 6, lane = t & 63;
  int wr = (wave >> 1) * 64, wc = (wave & 1) * 64;
  int lm = lane & 15, lq = lane >> 4;
  int srow = t >> 2;            // 0..63
  int scol = (t & 3) * 8;       // 0,8,16,24
  size_t r0 = (size_t)(m_base + m0 + srow) * 256;
  size_t r1 = (size_t)(m_base + m0 + 64 + srow) * 256;
  fx4 acc[4][4] = {};
  for (int kk = 0; kk < 256; kk += 32){
    uint4 pa0, pa1;
    if (isf32){
      const float* a0p = (const float*)A + r0 + kk + scol;
      const float* a1p = (const float*)A + r1 + kk + scol;
      float4 va0a = *(const float4*)(a0p);
      float4 va0b = *(const float4*)(a0p + 4);
      float4 va1a = *(const float4*)(a1p);
      float4 va1b = *(const float4*)(a1p + 4);
      pa0.x = pack2(va0a.x, va0a.y); pa0.y = pack2(va0a.z, va0a.w);
      pa0.z = pack2(va0b.x, va0b.y); pa0.w = pack2(va0b.z, va0b.w);
      pa1.x = pack2(va1a.x, va1a.y); pa1.y = pack2(va1a.z, va1a.w);
      pa1.z = pack2(va1b.x, va1b.y); pa1.w = pack2(va1b.z, va1b.w);
    } else {
      pa0 = *(const uint4*)((const bf16*)A + r0 + kk + scol);
      pa1 = *(const uint4*)((const bf16*)A + r1 + kk + scol);
    }
    float4 vb0 = *(const float4*)(BT + (size_t)(n0 + srow)      * 256 + kk + scol);
    float4 vb1 = *(const float4*)(BT + (size_t)(n0 + 64 + srow) * 256 + kk + scol);
    __syncthreads();
    *(uint4*)(As + srow*40 + scol)         = pa0;
    *(uint4*)(As + (64 + srow)*40 + scol)  = pa1;
    *(float4*)(Bs + srow*40 + scol)        = vb0;
    *(float4*)(Bs + (64 + srow)*40 + scol) = vb1;
    __syncthreads();
    bh8 af[4], bfr[4];
    #pragma unroll
    for (int mt = 0; mt < 4; mt++)
      af[mt] = *reinterpret_cast<const bh8*>(As + (wr + mt*16 + lm)*40 + lq*8);
    #pragma unroll
    for (int nt = 0; nt < 4; nt++)
      bfr[nt] = *reinterpret_cast<const bh8*>(Bs + (wc + nt*16 + lm)*40 + lq*8);
    #pragma unroll
    for (int mt = 0; mt < 4; mt++)
      #pragma unroll
      for (int nt = 0; nt < 4; nt++)
        acc[mt][nt] = __builtin_amdgcn_mfma_f32_16x16x32_bf16(af[mt], bfr[nt], acc[mt][nt], 0, 0, 0);
  }
  #pragma unroll
  for (int mt = 0; mt < 4; mt++)
    #pragma unroll
    for (int nt = 0; nt < 4; nt++)
      #pragma unroll
      for (int r = 0; r < 4; r++){
        int row = m0 + wr + mt*16 + lq*4 + r;
        int col = n0 + wc + nt*16 + lm;
        C[(size_t)row*256 + col] = __float2bfloat16(acc[mt][nt][r]);
      }
}

// ---- logits: block = 32 edges; coalesced LDS staging then (e,h)-thread dot ----
__global__ __launch_bounds__(256) void k_logits(
    const bf16* __restrict__ He, const float* __restrict__ Pni, const float* __restrict__ Pnj,
    const float* __restrict__ biasH, const float* __restrict__ ap, const int* __restrict__ ei,
    float* __restrict__ logits, unsigned* __restrict__ mkey, int e0chunk)
{
  __shared__ float hs[32*264];    // row stride 264, head slot stride 33: bank = 8e+h+i
  __shared__ int   ssh[32], dsh[32];
  __shared__ float aps[256], bhs[256];
  int t = threadIdx.x;
  int base = e0chunk + blockIdx.x*32;
  if (t < 32) ssh[t] = ei[base + t];
  else if (t < 64) dsh[t-32] = ei[E_ + base + (t - 32)];
  aps[t] = ap[t];
  bhs[t] = biasH[t];
  __syncthreads();
  int slot = (t >> 5)*33 + (t & 31);
  for (int r = 0; r < 32; r++){
    float v = b2f(He[(size_t)(base - e0chunk + r)*256 + t])
            + Pni[ssh[r]*256 + t] + Pnj[dsh[r]*256 + t] + bhs[t];
    v = (v > 0.f) ? v : 0.2f*v;       // leaky_relu 0.2
    hs[r*264 + slot] = v;
  }
  __syncthreads();
  int e = t >> 3, h = t & 7;
  const float* hr  = hs + e*264 + h*33;
  const float* apr = aps + h*32;
  float acc = 0.f;
  #pragma unroll
  for (int i = 0; i < 32; i++) acc = fmaf(hr[i], apr[i], acc);
  logits[(size_t)(base + e)*8 + h] = acc;
  unsigned ub = __float_as_uint(acc);
  unsigned key = (ub & 0x80000000u) ? ~ub : (ub | 0x80000000u);
  atomicMax(&mkey[ssh[e]*8 + h], key);
}

__global__ __launch_bounds__(256) void k_softden(
    const int* __restrict__ ei, float* __restrict__ logits,
    const unsigned* __restrict__ mkey, float* __restrict__ denom)
{
  int gid = blockIdx.x*256 + threadIdx.x;
  int e = gid >> 3, h = gid & 7;
  int s = ei[e];
  unsigned key = mkey[s*8 + h];
  unsigned ub = (key & 0x80000000u) ? (key & 0x7FFFFFFFu) : ~key;
  float m = __uint_as_float(ub);
  float a = fminf(logits[gid] - m, 0.f);
  float z = __expf(a);
  logits[gid] = z;
  atomicAdd(&denom[s*8 + h], z);
}

__global__ __launch_bounds__(256) void k_agg(
    const int* __restrict__ offs, const int* __restrict__ eorder, const int* __restrict__ ei,
    const float* __restrict__ z, const float* __restrict__ denom,
    const void* __restrict__ ef, const int* __restrict__ dflag,
    const float* __restrict__ Pmsg, const float* __restrict__ bmsg,
    const float* __restrict__ Wmsg,
    const void* __restrict__ nodes, const float* __restrict__ Wg, const float* __restrict__ bg,
    const float* __restrict__ g2, const float* __restrict__ b2v,
    const float* __restrict__ Wq, const float* __restrict__ bq,
    float* __restrict__ nodes1, float* __restrict__ qbuf)
{
  __shared__ float zsh[32*8];
  __shared__ int   esh[32];
  __shared__ int   dsh[32];
  __shared__ float sinv[8];
  __shared__ float Fs[8*257];
  __shared__ float aggs[256];
  __shared__ float r1[4], r2[4];
  int n = blockIdx.x, t = threadIdx.x;
  bool isf32 = (*dflag != 0);
  int h = t >> 5;
  int e0 = offs[n], e1 = offs[n+1];
  if (t < 8){
    float dsum = denom[n*8 + t];
    sinv[t] = (dsum > 0.f) ? 1.f/dsum : 0.f;
  }
  float facc[8] = {};
  float gacc = 0.f;
  int jz = t >> 3, hz = t & 7;
  for (int base = e0; base < e1; base += 32){
    int cnt = min(32, e1 - base);
    __syncthreads();
    if (t < cnt){ int e = eorder[base + t]; esh[t] = e; dsh[t] = ei[E_ + e]; }
    __syncthreads();
    if (jz < cnt) zsh[t] = z[(size_t)esh[jz]*8 + hz];
    __syncthreads();
    for (int jj = 0; jj < cnt; jj++){
      int e = esh[jj];
      float efv = ldf(ef, (size_t)e*256 + t, isf32);
      #pragma unroll
      for (int hq = 0; hq < 8; hq++) facc[hq] = fmaf(zsh[jj*8 + hq], efv, facc[hq]);
      gacc = fmaf(zsh[jj*8 + h], Pmsg[dsh[jj]*256 + t], gacc);
    }
  }
  __syncthreads();
  #pragma unroll
  for (int hq = 0; hq < 8; hq++) Fs[hq*257 + t] = facc[hq] * sinv[hq];
  __syncthreads();
  float am = gacc * sinv[h] + bmsg[t];
  const float* fr = Fs + h*257;
  for (int k = 0; k < 256; k++)
    am = fmaf(fr[k], Wmsg[(size_t)(256 + k)*256 + t], am);
  aggs[t] = am;
  __syncthreads();
  float o = bg[t] + ldf(nodes, (size_t)n*256 + t, isf32);
  for (int k = 0; k < 256; k++) o = fmaf(aggs[k], Wg[k*256 + t], o);
  nodes1[n*256 + t] = o;
  float mu, rstd;
  ln_stats(o, t, r1, r2, mu, rstd);
  float x2 = (o - mu) * rstd * g2[t] + b2v[t];
  __syncthreads();
  aggs[t] = x2;
  __syncthreads();
  float q = bq[t];
  for (int k = 0; k < 256; k++) q = fmaf(aggs[k], Wq[k*256 + t], q);
  qbuf[n*256 + t] = q;
}

__global__ __launch_bounds__(256) void k_kv(
    const void* __restrict__ images, const int* __restrict__ dflag,
    const float* __restrict__ Wkv, const float* __restrict__ bkv,
    float* __restrict__ kbuf, float* __restrict__ vT)
{
  __shared__ float im[256];
  int bk = blockIdx.x;
  int b = bk >> 10, ki = bk & 1023;
  int t = threadIdx.x;
  bool isf32 = (*dflag != 0);
  im[t] = ldf(images, (size_t)bk*256 + t, isf32);
  __syncthreads();
  float ko = bkv[t], vo = bkv[256 + t];
  for (int j = 0; j < 256; j++){
    float x = im[j];
    ko = fmaf(x, Wkv[j*512 + t], ko);
    vo = fmaf(x, Wkv[j*512 + 256 + t], vo);
  }
  kbuf[(size_t)bk*256 + t] = ko;
  int h = t >> 5, d = t & 31;
  vT[(((size_t)b*NH_ + h)*32 + d)*NK_ + ki] = vo;
}

__global__ __launch_bounds__(256) void k_cpb(
    const void* __restrict__ rel, const int* __restrict__ dflag,
    const float* __restrict__ Wc1, const float* __restrict__ bc1,
    const float* __restrict__ Wc2, const float* __restrict__ bc2, bf16* __restrict__ bias)
{
  __shared__ float w0[256], w1[256], bb[256], w2[256*8], b2s[8];
  int t = threadIdx.x;
  bool isf32 = (*dflag != 0);
  w0[t] = Wc1[t]; w1[t] = Wc1[256 + t]; bb[t] = bc1[t];
  for (int i = t; i < 2048; i += 256) w2[i] = Wc2[i];
  if (t < 8) b2s[t] = bc2[t];
  __syncthreads();
  size_t pos = (size_t)blockIdx.x*256 + t;
  float c0 = ldf(rel, pos*2, isf32), c1 = ldf(rel, pos*2 + 1, isf32);
  float acc[8] = {};
  for (int j = 0; j < 256; j++){
    float hj = fmaf(c0, w0[j], fmaf(c1, w1[j], bb[j]));
    hj = fmaxf(hj, 0.f);
    #pragma unroll
    for (int h = 0; h < 8; h++) acc[h] = fmaf(hj, w2[j*8 + h], acc[h]);
  }
  int k = (int)(pos & 1023);
  size_t qq = pos >> 10;
  size_t b = qq / NQ_, q = qq % NQ_;
  bf16* dst = bias + ((b*NH_)*NQ_ + q)*NK_;
  #pragma unroll
  for (int h = 0; h < 8; h++)
    dst[(size_t)h*NQ_*NK_ + k] = __float2bfloat16(acc[h] + b2s[h]);
}

// ---- cross attention: block per (qtile=8, h, b); LDS-staged K/V, block softmax ----
__global__ __launch_bounds__(256) void k_attn(
    const float* __restrict__ qbuf, const float* __restrict__ kbuf, const float* __restrict__ vT,
    const bf16* __restrict__ bias, float* __restrict__ attn_out)
{
  __shared__ float Qs[8*33];
  __shared__ float Ks[128*33];      // K tile, reused as V tile
  __shared__ float Sc[8*1024];
  __shared__ float Op[4*8*32];
  __shared__ float qs[8];
  int qt = blockIdx.x, h = blockIdx.y, b = blockIdx.z;
  int q0 = qt*8;
  int t = threadIdx.x;
  {
    int q = t >> 5, d = t & 31;
    int gq = q0 + q;
    Qs[q*33 + d] = (gq < NQ_) ? qbuf[((size_t)b*NQ_ + gq)*256 + h*32 + d] : 0.f;
  }
  const float* kbase = kbuf + (size_t)b*NK_*256 + h*32;
  const bf16*  bb    = bias + ((size_t)(b*NH_ + h)*NQ_)*NK_;
  int kl = t & 127;
  int qb = (t >> 7) * 4;
  // ---- scores ----
  for (int kt = 0; kt < 8; kt++){
    int k0 = kt*128;
    __syncthreads();
    { // stage K tile (coalesced float4 reads; 128B = exactly the h-slice of each row)
      int r = t >> 1, c0 = (t & 1) * 16;
      const float* src = kbase + (size_t)(k0 + r)*256 + c0;
      float* dst = Ks + r*33 + c0;
      #pragma unroll
      for (int ii = 0; ii < 4; ii++){
        float4 f = *(const float4*)(src + ii*4);
        dst[ii*4+0]=f.x; dst[ii*4+1]=f.y; dst[ii*4+2]=f.z; dst[ii*4+3]=f.w;
      }
    }
    __syncthreads();
    float a0=0.f, a1=0.f, a2=0.f, a3=0.f;
    const float* kr = Ks + kl*33;
    #pragma unroll
    for (int i = 0; i < 32; i++){
      float kd = kr[i];
      a0 = fmaf(kd, Qs[(qb+0)*33+i], a0);
      a1 = fmaf(kd, Qs[(qb+1)*33+i], a1);
      a2 = fmaf(kd, Qs[(qb+2)*33+i], a2);
      a3 = fmaf(kd, Qs[(qb+3)*33+i], a3);
    }
    float av[4] = {a0,a1,a2,a3};
    #pragma unroll
    for (int j = 0; j < 4; j++){
      int gq = min(q0 + qb + j, NQ_-1);     // clamp pad rows into valid bias
      float s = av[j]*0.17677669529663689f + b2f(bb[(size_t)gq*NK_ + k0 + kl]);
      Sc[(qb+j)*1024 + k0 + kl] = s;
    }
  }
  __syncthreads();
  // ---- per-q softmax (max, exp, sum) ----
  {
    int q = t >> 5, j = t & 31;
    float m = -1e30f;
    for (int k = j; k < 1024; k += 32) m = fmaxf(m, Sc[q*1024 + k]);
    #pragma unroll
    for (int o = 16; o; o >>= 1) m = fmaxf(m, __shfl_xor(m, o));
    float ssum = 0.f;
    for (int k = j; k < 1024; k += 32){
      float e = __expf(Sc[q*1024 + k] - m);
      Sc[q*1024 + k] = e;
      ssum += e;
    }
    #pragma unroll
    for (int o = 16; o; o >>= 1) ssum += __shfl_xor(ssum, o);
    if (j == 0) qs[q] = ssum;
  }
  // ---- PV: thread = (d, qg of 4 q's, k-quarter); 1 V-read feeds 4 accumulators ----
  int d = t & 31, qg = (t >> 5) & 1, ks = t >> 6;
  const float* vrb = vT + (((size_t)(b*NH_ + h))*32)*NK_;
  float o0=0.f, o1=0.f, o2=0.f, o3=0.f;
  for (int kt = 0; kt < 8; kt++){
    int k0 = kt*128;
    __syncthreads();
    { // stage V tile: Vs[k][d] from vT[bh][d][k] (coalesced along k)
      int d2 = t >> 3, kq = (t & 7) * 16;
      const float* src = vrb + (size_t)d2*NK_ + k0 + kq;
      #pragma unroll
      for (int ii = 0; ii < 4; ii++){
        float4 f = *(const float4*)(src + ii*4);
        Ks[(kq+ii*4+0)*33 + d2] = f.x;
        Ks[(kq+ii*4+1)*33 + d2] = f.y;
        Ks[(kq+ii*4+2)*33 + d2] = f.z;
        Ks[(kq+ii*4+3)*33 + d2] = f.w;
      }
    }
    __syncthreads();
    const float* sc0 = Sc + (qg*4+0)*1024 + k0 + ks*32;
    const float* sc1 = Sc + (qg*4+1)*1024 + k0 + ks*32;
    const float* sc2 = Sc + (qg*4+2)*1024 + k0 + ks*32;
    const float* sc3 = Sc + (qg*4+3)*1024 + k0 + ks*32;
    #pragma unroll
    for (int kk = 0; kk < 32; kk++){
      float vv = Ks[(ks*32+kk)*33 + d];
      o0 = fmaf(sc0[kk], vv, o0);
      o1 = fmaf(sc1[kk], vv, o1);
      o2 = fmaf(sc2[kk], vv, o2);
      o3 = fmaf(sc3[kk], vv, o3);
    }
  }
  Op[((ks*8) + qg*4 + 0)*32 + d] = o0;
  Op[((ks*8) + qg*4 + 1)*32 + d] = o1;
  Op[((ks*8) + qg*4 + 2)*32 + d] = o2;
  Op[((ks*8) + qg*4 + 3)*32 + d] = o3;
  __syncthreads();
  {
    int q = t >> 5, dd = t & 31;
    int gq = q0 + q;
    if (gq < NQ_){
      float s = Op[(0*8+q)*32+dd] + Op[(1*8+q)*32+dd]
              + Op[(2*8+q)*32+dd] + Op[(3*8+q)*32+dd];
      attn_out[(((size_t)b*NH_ + h)*NQ_ + gq)*32 + dd] = s / qs[q];
    }
  }
}

__global__ __launch_bounds__(256) void k_final(
    const float* __restrict__ attn_out, const float* __restrict__ nodes1,
    const float* __restrict__ Wco, const float* __restrict__ bco,
    const float* __restrict__ g3, const float* __restrict__ b3,
    const float* __restrict__ Wf1, const float* __restrict__ bf1v,
    const float* __restrict__ Wf2, const float* __restrict__ bf2v,
    float* __restrict__ out)
{
  __shared__ float ybuf[256];
  __shared__ float x3s[256];
  __shared__ float f1s[1024];
  __shared__ float r1[4], r2[4];
  int n = blockIdx.x;
  int b = n / NQ_, qp = n % NQ_;
  int t = threadIdx.x;
  int j = t >> 5, d = t & 31;
  int tt = qp*8 + j;
  int hj = tt / NQ_, qj = tt % NQ_;
  ybuf[t] = attn_out[(((size_t)b*NH_ + hj)*NQ_ + qj)*32 + d];
  __syncthreads();
  float o = bco[t];
  for (int k = 0; k < 256; k++) o = fmaf(ybuf[k], Wco[k*256 + t], o);
  float n2 = nodes1[n*256 + t] + o;
  float mu, rstd;
  ln_stats(n2, t, r1, r2, mu, rstd);
  float x3 = (n2 - mu) * rstd * g3[t] + b3[t];
  x3s[t] = x3;
  __syncthreads();
  float a0 = bf1v[t], a1 = bf1v[256 + t], a2 = bf1v[512 + t], a3 = bf1v[768 + t];
  for (int k = 0; k < 256; k++){
    float xv = x3s[k];
    const float* wr = Wf1 + (size_t)k*1024;
    a0 = fmaf(xv, wr[t],       a0);
    a1 = fmaf(xv, wr[256 + t], a1);
    a2 = fmaf(xv, wr[512 + t], a2);
    a3 = fmaf(xv, wr[768 + t], a3);
  }
  const float c = 0.70710678118654752f;
  f1s[t]       = 0.5f*a0*(1.f + erff(a0*c));
  f1s[256 + t] = 0.5f*a1*(1.f + erff(a1*c));
  f1s[512 + t] = 0.5f*a2*(1.f + erff(a2*c));
  f1s[768 + t] = 0.5f*a3*(1.f + erff(a3*c));
  __syncthreads();
  float r = bf2v[t] + x3s[t];
  for (int k = 0; k < 1024; k++) r = fmaf(f1s[k], Wf2[(size_t)k*256 + t], r);
  out[n*256 + t] = r;
}

extern "C" void kernel_launch(void* const* d_in, const int* in_sizes, int n_in,
                              void* d_out, int out_size, void* d_ws, size_t ws_size,
                              hipStream_t stream)
{
  const void* nodes  = d_in[0];
  const void* images = d_in[1];
  const void* rel    = d_in[2];
  const void* ef     = d_in[3];
  const int*  ei     = (const int*)d_in[4];
  float* out = (float*)d_out;

  char* w = (char*)d_ws;
  auto alloc = [&](size_t bytes) -> void* {
    void* p = (void*)w; w += (bytes + 255) & ~(size_t)255; return p;
  };
  int*      dflag  = (int*)     alloc(4);
  float*    Wall   = (float*)   alloc((size_t)WTOT*4);
  bf16*     He     = (bf16*)    alloc((size_t)CH_*256*2);
  bf16*     bias   = (bf16*)    alloc((size_t)NB_*NH_*NQ_*NK_*2);
  float*    logits = (float*)   alloc((size_t)E_*8*4);
  float*    Pni    = (float*)   alloc(N_*256*4);
  float*    Pnj    = (float*)   alloc(N_*256*4);
  float*    Pmsg   = (float*)   alloc(N_*256*4);
  float*    biasH  = (float*)   alloc(256*4);
  float*    nodes1 = (float*)   alloc(N_*256*4);
  float*    qbuf   = (float*)   alloc(N_*256*4);
  float*    kbuf   = (float*)   alloc((size_t)NB_*NK_*256*4);
  float*    vT     = (float*)   alloc((size_t)NB_*NH_*32*NK_*4);
  float*    attn_o = (float*)   alloc((size_t)NB_*NH_*NQ_*32*4);
  unsigned* mkey   = (unsigned*)alloc(N_*8*4);
  float*    denom  = (float*)   alloc(N_*8*4);
  int*      cnt    = (int*)     alloc(N_*4);
  int*      offs   = (int*)     alloc((N_+1)*4);
  int*      cursor = (int*)     alloc(N_*4);
  int*      eorder = (int*)     alloc((size_t)E_*4);
  bf16*     WeT    = (bf16*)    alloc(256*256*2);
  // total ~= 35.5 MB

  const float *ln1g=Wall+WOFF[0],  *ln1b=Wall+WOFF[1];
  const float *ln2g=Wall+WOFF[2],  *ln2b=Wall+WOFF[3];
  const float *ln3g=Wall+WOFF[4],  *ln3b=Wall+WOFF[5];
  const float *Wni=Wall+WOFF[6],  *bni=Wall+WOFF[7];
  const float *Wnj=Wall+WOFF[8],  *bnj=Wall+WOFF[9];
  const float *be =Wall+WOFF[10], *ap =Wall+WOFF[11];
  const float *Wmsg=Wall+WOFF[12], *bmsg=Wall+WOFF[13];
  const float *Wg=Wall+WOFF[14], *bg=Wall+WOFF[15];
  const float *Wq=Wall+WOFF[16], *bq=Wall+WOFF[17];
  const float *Wkv=Wall+WOFF[18], *bkv=Wall+WOFF[19];
  const float *Wc1=Wall+WOFF[20], *bc1=Wall+WOFF[21];
  const float *Wc2=Wall+WOFF[22], *bc2=Wall+WOFF[23];
  const float *Wco=Wall+WOFF[24], *bco=Wall+WOFF[25];
  const float *Wf1=Wall+WOFF[26], *bf1v=Wall+WOFF[27];
  const float *Wf2=Wall+WOFF[28], *bf2v=Wall+WOFF[29];

  SrcTab tab;
  {
    const int idx[NWSEG] = {6,7,8,9,10,11, 12,13,14,15, 17,18, 19,20, 21,22,23,24,
                            25,26, 27,28,29,30, 31,32, 33,34,35,36};
    for (int i = 0; i < NWSEG; i++) tab.p[i] = d_in[idx[i]];
  }

  k_init    <<<19, 256, 0, stream>>>(cnt, mkey, denom, nodes, dflag);
  k_cvt     <<<(WTOT+255)/256, 256, 0, stream>>>(tab, Wall, dflag);
  k_node_pre<<<N_, 256, 0, stream>>>(nodes, dflag, ln1g, ln1b, Wni, Wnj, Wmsg, Pni, Pnj, Pmsg);
  k_prep    <<<256, 256, 0, stream>>>(d_in[16], dflag, bni, bnj, be, WeT, biasH);
  k_count   <<<E_/256, 256, 0, stream>>>(ei, cnt);
  k_scan    <<<1, 1024, 0, stream>>>(cnt, offs, cursor);
  k_scatter <<<E_/256, 256, 0, stream>>>(ei, cursor, eorder);

  dim3 ggrid(CH_/128, 2);
  for (int c = 0; c < E_/CH_; c++){
    k_gemm_dual<<<ggrid, 256, 0, stream>>>(ef, c*CH_, dflag, WeT, He);
    k_logits   <<<CH_/32, 256, 0, stream>>>(He, Pni, Pnj, biasH, ap, ei, logits, mkey, c*CH_);
  }
  k_softden <<<E_*8/256, 256, 0, stream>>>(ei, logits, mkey, denom);
  k_agg     <<<N_, 256, 0, stream>>>(offs, eorder, ei, logits, denom, ef, dflag, Pmsg, bmsg, Wmsg,
                                     nodes, Wg, bg, ln2g, ln2b, Wq, bq, nodes1, qbuf);
  k_kv      <<<NB_*NK_, 256, 0, stream>>>(images, dflag, Wkv, bkv, kbuf, vT);
  k_cpb     <<<NB_*NQ_*NK_/256, 256, 0, stream>>>(rel, dflag, Wc1, bc1, Wc2, bc2, bias);
  dim3 agrid((NQ_ + 7)/8, NH_, NB_);
  k_attn    <<<agrid, 256, 0, stream>>>(qbuf, kbuf, vT, bias, attn_o);
  k_final   <<<N_, 256, 0, stream>>>(attn_o, nodes1, Wco, bco, ln3g, ln3b,
                                     Wf1, bf1v, Wf2, bf2v, out);
}